// Round 6
// baseline (58720.026 us; speedup 1.0000x reference)
//
#include <hip/hip_runtime.h>
#include <stdint.h>

#define T_STEPS 2048
#define BATCH   16
#define DIM     1024
#define BD      (BATCH * DIM)
#define PAIRS   512                 // value-pairs per batch
#define HXP     (BATCH * PAIRS)     // u64 slots per parity buffer

typedef float    f32x4 __attribute__((ext_vector_type(4)));
typedef unsigned u32x4 __attribute__((ext_vector_type(4)));
typedef __bf16   bf16x8 __attribute__((ext_vector_type(8)));

__device__ __forceinline__ unsigned bf16b(float f) {
  __bf16 b = (__bf16)f; unsigned short s; __builtin_memcpy(&s, &b, 2);
  return (unsigned)s;
}

// ---------------------------------------------------------------------------
// ws: [0,128KB) hX = u64[2][B][512] tagged bf16-pair h; [128KB,+256B) ctr u32[16][4]
// ---------------------------------------------------------------------------
__global__ void prep_kernel(const float* __restrict__ h0,
                            float* __restrict__ hout,
                            unsigned long long* __restrict__ hX,
                            unsigned* __restrict__ ctr) {
  int i = blockIdx.x * blockDim.x + threadIdx.x;
  if (i < BD) hout[i] = h0[i];
  if (i < HXP) {
    int b = i >> 9, j = i & 511;
    float v0 = h0[b * DIM + 2 * j], v1 = h0[b * DIM + 2 * j + 1];
    hX[i] = (unsigned long long)(bf16b(v0) | (bf16b(v1) << 16));  // tag 0
    hX[HXP + i] = 0xFFFFFFFF00000000ull;                          // invalid
  }
  if (i < 64) ctr[i] = 0u;
}

// ---------------------------------------------------------------------------
// xp = x @ W_x^T + b  (R1-proven)
// ---------------------------------------------------------------------------
__global__ __launch_bounds__(256)
void xp_gemm(const float* __restrict__ X, const float* __restrict__ W,
             const float* __restrict__ Bv, float* __restrict__ XP) {
  __shared__ __bf16 As[128 * 64];
  __shared__ __bf16 Bs[128 * 64];
  const int tid = threadIdx.x;
  const int bm = blockIdx.x & 255;
  const int bn = blockIdx.x >> 8;
  const int w = tid >> 6, l = tid & 63;
  const int wr = w >> 1, wc = w & 1;
  const int sr = tid >> 1, sh = tid & 1;

  const float* xrow = X + (size_t)(bm * 128 + sr) * DIM + sh * 32;
  const float* wrow = W + (size_t)(bn * 128 + sr) * DIM + sh * 32;
  char* AsB = (char*)As;
  char* BsB = (char*)Bs;
  const int swr  = sr * 128;
  const int swzs = (sr & 7) << 4;

  f32x4 acc[4][4];
  const f32x4 z4 = {0.f, 0.f, 0.f, 0.f};
#pragma unroll
  for (int i = 0; i < 4; ++i)
#pragma unroll
    for (int j = 0; j < 4; ++j) acc[i][j] = z4;

  for (int kt = 0; kt < 16; ++kt) {
#pragma unroll
    for (int j = 0; j < 8; ++j) {
      f32x4 a  = *(const f32x4*)(xrow + kt * 64 + 4 * j);
      f32x4 bv = *(const f32x4*)(wrow + kt * 64 + 4 * j);
      union { __bf16 h[4]; unsigned long long u; } pa, pb;
#pragma unroll
      for (int qq = 0; qq < 4; ++qq) { pa.h[qq] = (__bf16)a[qq]; pb.h[qq] = (__bf16)bv[qq]; }
      int c2  = (sh * 32 + 4 * j) * 2;
      int off = swr + (c2 ^ swzs);
      *(unsigned long long*)(AsB + off) = pa.u;
      *(unsigned long long*)(BsB + off) = pb.u;
    }
    __syncthreads();
#pragma unroll
    for (int ks = 0; ks < 2; ++ks) {
      bf16x8 afr[4], bfr[4];
#pragma unroll
      for (int mi = 0; mi < 4; ++mi) {
        int row = wr * 64 + mi * 16 + (l & 15);
        int c2  = ks * 64 + (l >> 4) * 16;
        afr[mi] = *(const bf16x8*)(AsB + row * 128 + (c2 ^ ((row & 7) << 4)));
      }
#pragma unroll
      for (int ni = 0; ni < 4; ++ni) {
        int row = wc * 64 + ni * 16 + (l & 15);
        int c2  = ks * 64 + (l >> 4) * 16;
        bfr[ni] = *(const bf16x8*)(BsB + row * 128 + (c2 ^ ((row & 7) << 4)));
      }
#pragma unroll
      for (int mi = 0; mi < 4; ++mi)
#pragma unroll
        for (int ni = 0; ni < 4; ++ni)
          acc[mi][ni] = __builtin_amdgcn_mfma_f32_16x16x32_bf16(
              afr[mi], bfr[ni], acc[mi][ni], 0, 0, 0);
    }
    __syncthreads();
  }
  const int colb = bn * 128 + wc * 64 + (l & 15);
#pragma unroll
  for (int ni = 0; ni < 4; ++ni) {
    int col = colb + ni * 16;
    float bb = Bv[col];
#pragma unroll
    for (int mi = 0; mi < 4; ++mi) {
      int row = bm * 128 + wr * 64 + mi * 16 + ((l >> 4) << 2);
#pragma unroll
      for (int r = 0; r < 4; ++r)
        XP[(size_t)(row + r) * DIM + col] = acc[mi][ni][r] + bb;
    }
  }
}

// ---------------------------------------------------------------------------
// recurrence: counter-released tagged exchange.
//   producer: pair stores (sc1) -> s_waitcnt vmcnt(0) [= MALL-visible ACK]
//             -> relaxed atomicAdd to ctr[b][w&3].
//   consumer (wave 0): spin on 16B of counters (>= 4t) -> one 4KB bulk load
//             (tag-validated, expected 0 retries) -> unpack bf16 -> LDS.
// ---------------------------------------------------------------------------
__global__ __launch_bounds__(1024, 4)
void rnn_kernel(const float* __restrict__ Wh, const float* __restrict__ Z,
                const float* __restrict__ gz, const float* __restrict__ gh,
                const float* __restrict__ bg,
                float* __restrict__ out,    // holds xp, overwritten with out
                float* __restrict__ hout,   // [T+1][B][D]
                unsigned long long* __restrict__ hX,
                unsigned* __restrict__ ctr) {
  __shared__ float hb[2][1024];
  const int tid = threadIdx.x;
  const int w   = tid >> 6;
  const int l   = tid & 63;
  const int b   = blockIdx.x >> 4;
  const int s   = blockIdx.x & 15;
  const int r0  = s * 64;
  const int myrow  = r0 + w * 4 + (l & 3);
  const bool writer = (l < 4);

  // W_h slice -> registers: wave w rows r0+4w..+3, lane l K-range [16l,16l+16)
  f32x4 W4[4][4];
  {
    const f32x4* WhV = (const f32x4*)Wh;
#pragma unroll
    for (int r4 = 0; r4 < 4; ++r4) {
      size_t base = (size_t)(r0 + w * 4 + r4) * (DIM / 4) + l * 4;
#pragma unroll
      for (int jj = 0; jj < 4; ++jj) W4[r4][jj] = WhV[base + jj];
    }
  }

  float cgz = 0.f, cgh = 0.f, cbg = 0.f, xp_n = 0.f, z_n = 0.f;
  if (writer) {
    cgz = gz[myrow]; cgh = gh[myrow]; cbg = bg[myrow];
    xp_n = out[(size_t)b * DIM + myrow];   // xp[0,b,myrow]
    z_n  = Z[(size_t)b * DIM + myrow];
  }

  for (int t = 0; t < T_STEPS; ++t) {
    const int p  = t & 1;
    const int p1 = p ^ 1;
    const unsigned tt = (unsigned)t;
    const unsigned long long* src = hX + (size_t)p * HXP + (size_t)b * PAIRS;
    unsigned long long*       dst = hX + (size_t)p1 * HXP + (size_t)b * PAIRS;

    if (w == 0) {
      // 1) fine poll: 4 per-batch counters reach 4t => all 16 producers ACKed
      const unsigned tgt = 4u * tt;
      const unsigned* cp = ctr + (b << 2) + (l & 3);
      for (;;) {
        unsigned cv;
        asm volatile("global_load_dword %0, %1, off sc1\n\ts_waitcnt vmcnt(0)"
                     : "=v"(cv) : "v"(cp) : "memory");
        if (__all((int)(cv >= tgt))) break;
      }
      // 2) bulk data load: 64 lanes x 64B = 4KB (tags expected == t)
      const char* ap = (const char*)src + (l << 6);
      u32x4 q0, q1, q2, q3;
      for (;;) {
        asm volatile(
            "global_load_dwordx4 %[q0], %[a], off sc1\n\t"
            "global_load_dwordx4 %[q1], %[a], off offset:16 sc1\n\t"
            "global_load_dwordx4 %[q2], %[a], off offset:32 sc1\n\t"
            "global_load_dwordx4 %[q3], %[a], off offset:48 sc1\n\t"
            "s_waitcnt vmcnt(0)"
            : [q0]"=v"(q0), [q1]"=v"(q1), [q2]"=v"(q2), [q3]"=v"(q3)
            : [a]"v"(ap) : "memory");
        int ok = (q0.y == tt) & (q0.w == tt) & (q1.y == tt) & (q1.w == tt) &
                 (q2.y == tt) & (q2.w == tt) & (q3.y == tt) & (q3.w == tt);
        if (__all(ok)) break;
      }
      // 3) unpack bf16 pairs -> f32, scatter to 0-conflict swizzled LDS
#define SC(K, Q) { int qi = 4 * l + K; int wi = (qi ^ (qi >> 3)) << 2;        \
      f32x4 v; v.x = __uint_as_float(Q.x << 16);                              \
      v.y = __uint_as_float(Q.x & 0xFFFF0000u);                               \
      v.z = __uint_as_float(Q.z << 16);                                       \
      v.w = __uint_as_float(Q.z & 0xFFFF0000u);                               \
      *(f32x4*)&hb[p][wi] = v; }
      SC(0, q0) SC(1, q1) SC(2, q2) SC(3, q3)
#undef SC
    }
    __syncthreads();

    // matvec: 64 FMA/thread from swizzled LDS (0-conflict, R5-verified)
    float acc0 = 0.f, acc1 = 0.f, acc2 = 0.f, acc3 = 0.f;
#pragma unroll
    for (int jj = 0; jj < 4; ++jj) {
      int qr = 4 * l + jj;
      int wb = ((qr ^ (qr >> 3)) & 255) << 2;
      f32x4 h4 = *(const f32x4*)&hb[p][wb];
#pragma unroll
      for (int i = 0; i < 4; ++i) {
        acc0 = fmaf(W4[0][jj][i], h4[i], acc0);
        acc1 = fmaf(W4[1][jj][i], h4[i], acc1);
        acc2 = fmaf(W4[2][jj][i], h4[i], acc2);
        acc3 = fmaf(W4[3][jj][i], h4[i], acc3);
      }
    }
    // 7-shuffle multi-reduce: lane l ends with full 64-lane sum of acc_{l&3}
    float w01 = (l & 1) ? acc0 : acc1;
    float v01 = ((l & 1) ? acc1 : acc0) + __shfl_xor(w01, 1);
    float w23 = (l & 1) ? acc2 : acc3;
    float v23 = ((l & 1) ? acc3 : acc2) + __shfl_xor(w23, 1);
    float wv  = (l & 2) ? v01 : v23;
    float vv  = ((l & 2) ? v23 : v01) + __shfl_xor(wv, 2);
    vv += __shfl_xor(vv, 4);
    vv += __shfl_xor(vv, 8);
    vv += __shfl_xor(vv, 16);
    vv += __shfl_xor(vv, 32);

    float hn = 0.f;
    if (writer) {
      float pre = vv + xp_n;
      float e2 = __expf(2.0f * pre);
      hn = 1.0f - 2.0f / (e2 + 1.0f);                // tanh, overflow-safe
      float hp = __shfl_xor(hn, 1);                  // partner row's h
      if ((l & 1) == 0) {                            // lanes 0,2 publish pairs
        unsigned payload = bf16b(hn) | (bf16b(hp) << 16);
        unsigned long long pk =
            ((unsigned long long)(unsigned)(t + 1) << 32) | payload;
        __hip_atomic_store(&dst[32 * s + 2 * w + (l >> 1)], pk,
                           __ATOMIC_RELAXED, __HIP_MEMORY_SCOPE_AGENT);
      }
    }
    // release: wait pair-store ACK (MALL-visible), then count this wave in
    asm volatile("s_waitcnt vmcnt(0)" ::: "memory");
    if (l == 0)
      __hip_atomic_fetch_add(&ctr[(b << 2) + (w & 3)], 1u,
                             __ATOMIC_RELAXED, __HIP_MEMORY_SCOPE_AGENT);
    if (writer) {
      hout[((size_t)(t + 1) * BATCH + b) * DIM + myrow] = hn;
      float y   = z_n * cgz + hn * cgh + cbg;
      float sig = 1.0f / (1.0f + __expf(-y));
      out[((size_t)t * BATCH + b) * DIM + myrow] = hn * (y * sig);
      if (t + 1 < T_STEPS) {   // prefetch next step's xp, z off the hot path
        xp_n = out[((size_t)(t + 1) * BATCH + b) * DIM + myrow];
        z_n  = Z[((size_t)(t + 1) * BATCH + b) * DIM + myrow];
      }
    }
  }
}

extern "C" void kernel_launch(void* const* d_in, const int* in_sizes, int n_in,
                              void* d_out, int out_size, void* d_ws, size_t ws_size,
                              hipStream_t stream) {
  const float* x    = (const float*)d_in[0];
  const float* z    = (const float*)d_in[1];
  const float* h0   = (const float*)d_in[2];
  const float* Wx   = (const float*)d_in[3];
  const float* Wh   = (const float*)d_in[4];
  const float* bias = (const float*)d_in[5];
  const float* gz   = (const float*)d_in[6];
  const float* gh   = (const float*)d_in[7];
  const float* bg   = (const float*)d_in[8];

  float* out  = (float*)d_out;
  float* hout = out + (size_t)T_STEPS * BATCH * DIM;
  unsigned long long* hX = (unsigned long long*)d_ws;           // 128 KB
  unsigned* ctr = (unsigned*)((char*)d_ws + 2ull * HXP * 8ull); // 256 B

  prep_kernel<<<dim3(64), dim3(256), 0, stream>>>(h0, hout, hX, ctr);
  xp_gemm<<<dim3(2048), dim3(256), 0, stream>>>(x, Wx, bias, out);
  rnn_kernel<<<dim3(256), dim3(1024), 0, stream>>>(Wh, z, gz, gh, bg, out, hout, hX, ctr);
}

// Round 7
// 6014.488 us; speedup vs baseline: 9.7631x; 9.7631x over previous
//
#include <hip/hip_runtime.h>
#include <stdint.h>

#define T_STEPS 2048
#define BATCH   16
#define DIM     1024
#define BD      (BATCH * DIM)

typedef float    f32x4 __attribute__((ext_vector_type(4)));
typedef unsigned u32x4 __attribute__((ext_vector_type(4)));
typedef __bf16   bf16x8 __attribute__((ext_vector_type(8)));

__device__ __forceinline__ unsigned bf16b(float f) {
  __bf16 b = (__bf16)f; unsigned short s; __builtin_memcpy(&s, &b, 2);
  return (unsigned)s;
}

// ---------------------------------------------------------------------------
// ws: [0,128KB) hX = u32[2][BATCH][DIM], each u32 = tag16<<16 | bf16(h)
// ---------------------------------------------------------------------------
__global__ void prep_kernel(const float* __restrict__ h0,
                            float* __restrict__ hout,
                            unsigned* __restrict__ hX32) {
  int i = blockIdx.x * blockDim.x + threadIdx.x;
  if (i < BD) {
    float v = h0[i];
    hout[i] = v;
    hX32[i] = bf16b(v);              // tag 0 | bf16(h0)
    hX32[BD + i] = 0xFFFF0000u;      // invalid tag
  }
}

// ---------------------------------------------------------------------------
// xp = x @ W_x^T + b  (R1-proven)
// ---------------------------------------------------------------------------
__global__ __launch_bounds__(256)
void xp_gemm(const float* __restrict__ X, const float* __restrict__ W,
             const float* __restrict__ Bv, float* __restrict__ XP) {
  __shared__ __bf16 As[128 * 64];
  __shared__ __bf16 Bs[128 * 64];
  const int tid = threadIdx.x;
  const int bm = blockIdx.x & 255;
  const int bn = blockIdx.x >> 8;
  const int w = tid >> 6, l = tid & 63;
  const int wr = w >> 1, wc = w & 1;
  const int sr = tid >> 1, sh = tid & 1;

  const float* xrow = X + (size_t)(bm * 128 + sr) * DIM + sh * 32;
  const float* wrow = W + (size_t)(bn * 128 + sr) * DIM + sh * 32;
  char* AsB = (char*)As;
  char* BsB = (char*)Bs;
  const int swr  = sr * 128;
  const int swzs = (sr & 7) << 4;

  f32x4 acc[4][4];
  const f32x4 z4 = {0.f, 0.f, 0.f, 0.f};
#pragma unroll
  for (int i = 0; i < 4; ++i)
#pragma unroll
    for (int j = 0; j < 4; ++j) acc[i][j] = z4;

  for (int kt = 0; kt < 16; ++kt) {
#pragma unroll
    for (int j = 0; j < 8; ++j) {
      f32x4 a  = *(const f32x4*)(xrow + kt * 64 + 4 * j);
      f32x4 bv = *(const f32x4*)(wrow + kt * 64 + 4 * j);
      union { __bf16 h[4]; unsigned long long u; } pa, pb;
#pragma unroll
      for (int qq = 0; qq < 4; ++qq) { pa.h[qq] = (__bf16)a[qq]; pb.h[qq] = (__bf16)bv[qq]; }
      int c2  = (sh * 32 + 4 * j) * 2;
      int off = swr + (c2 ^ swzs);
      *(unsigned long long*)(AsB + off) = pa.u;
      *(unsigned long long*)(BsB + off) = pb.u;
    }
    __syncthreads();
#pragma unroll
    for (int ks = 0; ks < 2; ++ks) {
      bf16x8 afr[4], bfr[4];
#pragma unroll
      for (int mi = 0; mi < 4; ++mi) {
        int row = wr * 64 + mi * 16 + (l & 15);
        int c2  = ks * 64 + (l >> 4) * 16;
        afr[mi] = *(const bf16x8*)(AsB + row * 128 + (c2 ^ ((row & 7) << 4)));
      }
#pragma unroll
      for (int ni = 0; ni < 4; ++ni) {
        int row = wc * 64 + ni * 16 + (l & 15);
        int c2  = ks * 64 + (l >> 4) * 16;
        bfr[ni] = *(const bf16x8*)(BsB + row * 128 + (c2 ^ ((row & 7) << 4)));
      }
#pragma unroll
      for (int mi = 0; mi < 4; ++mi)
#pragma unroll
        for (int ni = 0; ni < 4; ++ni)
          acc[mi][ni] = __builtin_amdgcn_mfma_f32_16x16x32_bf16(
              afr[mi], bfr[ni], acc[mi][ni], 0, 0, 0);
    }
    __syncthreads();
  }
  const int colb = bn * 128 + wc * 64 + (l & 15);
#pragma unroll
  for (int ni = 0; ni < 4; ++ni) {
    int col = colb + ni * 16;
    float bb = Bv[col];
#pragma unroll
    for (int mi = 0; mi < 4; ++mi) {
      int row = bm * 128 + wr * 64 + mi * 16 + ((l >> 4) << 2);
#pragma unroll
      for (int r = 0; r < 4; ++r)
        XP[(size_t)(row + r) * DIM + col] = acc[mi][ni][r] + bb;
    }
  }
}

// ---------------------------------------------------------------------------
// recurrence: R3 protocol (tag-validated data-carrying poll, parity dbuf),
// with u32 tag16|bf16 payload (4KB/batch), narrowing quad polls, 0-conflict
// LDS swizzle, atomic-swap publish.
// ---------------------------------------------------------------------------
__global__ __launch_bounds__(1024, 4)
void rnn_kernel(const float* __restrict__ Wh, const float* __restrict__ Z,
                const float* __restrict__ gz, const float* __restrict__ gh,
                const float* __restrict__ bg,
                float* __restrict__ out,    // holds xp, overwritten with out
                float* __restrict__ hout,   // [T+1][B][D]
                unsigned* __restrict__ hX32) {
  __shared__ float hb[2][1024];
  const int tid = threadIdx.x;
  const int w   = tid >> 6;
  const int l   = tid & 63;
  const int b   = blockIdx.x >> 4;
  const int s   = blockIdx.x & 15;
  const int r0  = s * 64;
  const int myrow  = r0 + w * 4 + (l & 3);
  const bool writer = (l < 4);

  // W_h slice -> registers: wave w rows r0+4w..+3, lane l K-range [16l,16l+16)
  f32x4 W4[4][4];
  {
    const f32x4* WhV = (const f32x4*)Wh;
#pragma unroll
    for (int r4 = 0; r4 < 4; ++r4) {
      size_t base = (size_t)(r0 + w * 4 + r4) * (DIM / 4) + l * 4;
#pragma unroll
      for (int jj = 0; jj < 4; ++jj) W4[r4][jj] = WhV[base + jj];
    }
  }

  float cgz = 0.f, cgh = 0.f, cbg = 0.f, xp_n = 0.f, z_n = 0.f;
  if (writer) {
    cgz = gz[myrow]; cgh = gh[myrow]; cbg = bg[myrow];
    xp_n = out[(size_t)b * DIM + myrow];   // xp[0,b,myrow]
    z_n  = Z[(size_t)b * DIM + myrow];
  }

  for (int t = 0; t < T_STEPS; ++t) {
    const int p  = t & 1;
    const int p1 = p ^ 1;
    const unsigned* src32 = hX32 + (size_t)p * BD + (size_t)b * DIM;
    unsigned*       dst32 = hX32 + (size_t)p1 * BD + (size_t)b * DIM;

    if (w == 0) {
      // narrowing poll: 4 quads of 1KB; re-load only quads not yet valid.
      // col c = 256k + 4l + i ; byte = 1024k + 16l + 4i. tag = hi16 == t.
      const char* ap = (const char*)src32 + (l << 4);
      const unsigned tt16 = (unsigned)(t & 0xFFFF);
      u32x4 q0, q1, q2, q3;
      unsigned pend = 0xFu;
      int rounds = 0;
#define SCAT(K, Q) { int qq = 64 * K + l; int wi = ((qq ^ (qq >> 3)) & 255) << 2; \
      f32x4 v; v.x = __uint_as_float(Q.x << 16); v.y = __uint_as_float(Q.y << 16); \
      v.z = __uint_as_float(Q.z << 16); v.w = __uint_as_float(Q.w << 16);          \
      *(f32x4*)&hb[p][wi] = v; }
#define TAGOK(Q) __all((int)(((Q.x >> 16) == tt16) & ((Q.y >> 16) == tt16) & \
                             ((Q.z >> 16) == tt16) & ((Q.w >> 16) == tt16)))
      do {
        if (pend & 1u)
          asm volatile("global_load_dwordx4 %0, %1, off sc1"
                       : "=v"(q0) : "v"(ap) : "memory");
        if (pend & 2u)
          asm volatile("global_load_dwordx4 %0, %1, off offset:1024 sc1"
                       : "=v"(q1) : "v"(ap) : "memory");
        if (pend & 4u)
          asm volatile("global_load_dwordx4 %0, %1, off offset:2048 sc1"
                       : "=v"(q2) : "v"(ap) : "memory");
        if (pend & 8u)
          asm volatile("global_load_dwordx4 %0, %1, off offset:3072 sc1"
                       : "=v"(q3) : "v"(ap) : "memory");
        asm volatile("s_waitcnt vmcnt(0)" ::: "memory");
        if ((pend & 1u) && TAGOK(q0)) { SCAT(0, q0); pend &= ~1u; }
        if ((pend & 2u) && TAGOK(q1)) { SCAT(1, q1); pend &= ~2u; }
        if ((pend & 4u) && TAGOK(q2)) { SCAT(2, q2); pend &= ~4u; }
        if ((pend & 8u) && TAGOK(q3)) { SCAT(3, q3); pend &= ~8u; }
      } while (pend && ++rounds < (1 << 22));
#undef SCAT
#undef TAGOK
    }
    __syncthreads();

    // matvec: 64 FMA/thread from swizzled LDS (0-conflict, R6-verified)
    float acc0 = 0.f, acc1 = 0.f, acc2 = 0.f, acc3 = 0.f;
#pragma unroll
    for (int jj = 0; jj < 4; ++jj) {
      int qr = 4 * l + jj;
      int wb = ((qr ^ (qr >> 3)) & 255) << 2;
      f32x4 h4 = *(const f32x4*)&hb[p][wb];
#pragma unroll
      for (int i = 0; i < 4; ++i) {
        acc0 = fmaf(W4[0][jj][i], h4[i], acc0);
        acc1 = fmaf(W4[1][jj][i], h4[i], acc1);
        acc2 = fmaf(W4[2][jj][i], h4[i], acc2);
        acc3 = fmaf(W4[3][jj][i], h4[i], acc3);
      }
    }
    // 7-shuffle multi-reduce: lane l ends with full 64-lane sum of acc_{l&3}
    float w01 = (l & 1) ? acc0 : acc1;
    float v01 = ((l & 1) ? acc1 : acc0) + __shfl_xor(w01, 1);
    float w23 = (l & 1) ? acc2 : acc3;
    float v23 = ((l & 1) ? acc3 : acc2) + __shfl_xor(w23, 1);
    float wv  = (l & 2) ? v01 : v23;
    float vv  = ((l & 2) ? v23 : v01) + __shfl_xor(wv, 2);
    vv += __shfl_xor(vv, 4);
    vv += __shfl_xor(vv, 8);
    vv += __shfl_xor(vv, 16);
    vv += __shfl_xor(vv, 32);

    if (writer) {
      float pre = vv + xp_n;
      float e2 = __expf(2.0f * pre);
      float hn = 1.0f - 2.0f / (e2 + 1.0f);          // tanh, overflow-safe
      // publish FIRST: atomic swap lands at the MALL coherence point
      unsigned pv = ((unsigned)((t + 1) & 0xFFFF) << 16) | bf16b(hn);
      unsigned* pp = dst32 + myrow;
      asm volatile("global_atomic_swap %0, %1, off"
                   :: "v"(pp), "v"(pv) : "memory");
      hout[((size_t)(t + 1) * BATCH + b) * DIM + myrow] = hn;
      float y   = z_n * cgz + hn * cgh + cbg;
      float sig = 1.0f / (1.0f + __expf(-y));
      out[((size_t)t * BATCH + b) * DIM + myrow] = hn * (y * sig);
      if (t + 1 < T_STEPS) {   // prefetch next step's xp, z off the hot path
        xp_n = out[((size_t)(t + 1) * BATCH + b) * DIM + myrow];
        z_n  = Z[((size_t)(t + 1) * BATCH + b) * DIM + myrow];
      }
    }
  }
}

extern "C" void kernel_launch(void* const* d_in, const int* in_sizes, int n_in,
                              void* d_out, int out_size, void* d_ws, size_t ws_size,
                              hipStream_t stream) {
  const float* x    = (const float*)d_in[0];
  const float* z    = (const float*)d_in[1];
  const float* h0   = (const float*)d_in[2];
  const float* Wx   = (const float*)d_in[3];
  const float* Wh   = (const float*)d_in[4];
  const float* bias = (const float*)d_in[5];
  const float* gz   = (const float*)d_in[6];
  const float* gh   = (const float*)d_in[7];
  const float* bg   = (const float*)d_in[8];

  float* out  = (float*)d_out;
  float* hout = out + (size_t)T_STEPS * BATCH * DIM;
  unsigned* hX32 = (unsigned*)d_ws;                  // 2*B*D*4 = 128 KB

  prep_kernel<<<dim3(64), dim3(256), 0, stream>>>(h0, hout, hX32);
  xp_gemm<<<dim3(2048), dim3(256), 0, stream>>>(x, Wx, bias, out);
  rnn_kernel<<<dim3(256), dim3(1024), 0, stream>>>(Wh, z, gz, gh, bg, out, hout, hX32);
}